// Round 7
// baseline (118.579 us; speedup 1.0000x reference)
//
#include <hip/hip_runtime.h>
#include <math.h>

#define N1 16384
#define N2 16384
#define BLOCK 256
#define PTS 8                          // pos1 points per thread (8 indep chains)
#define I_BLOCKS (N1 / (BLOCK * PTS))  // 8 blocks along pos1
#define QG 256                         // pos2 points per block
#define SGROUPS (N2 / QG)              // 64
#define GRID (I_BLOCKS * SGROUPS)      // 512 blocks = 2 blocks/CU
#define NCHUNK (QG / 64)               // 4 wave-chunks of pos2

typedef float v2f __attribute__((ext_vector_type(2)));

// order-preserving float<->uint mapping (for atomicMin over possibly-negative g)
static __device__ __forceinline__ unsigned int f2key(float f) {
    unsigned int b = __float_as_uint(f);
    return (b & 0x80000000u) ? ~b : (b | 0x80000000u);
}
static __device__ __forceinline__ float key2f(unsigned int k) {
    unsigned int b = (k & 0x80000000u) ? (k & 0x7FFFFFFFu) : ~k;
    return __uint_as_float(b);
}

// Single fused kernel.
// Phase 1: per (i-block, slice-group): min over 256 pos2 points of
//   g(q) = -2 p.q + |q|^2   (d^2 = |p|^2 + g; shift applied in phase 2).
// The pos2 chunk is loaded ONCE per wave (coalesced, per-lane) and broadcast
// lane->wave via v_readlane: the main loop has ZERO memory operations, so it
// runs at VALU issue rate regardless of load latency (the r2..r6 ~28us wall).
// Packed math: v_pk_fma_f32 computes g for 2 q's per instr; v_min3 folds them.
// Combine: device-scope atomicMin on 64 KB keys.
// Phase 2: last block (ticket) reduces keys -> mean.
__global__ __launch_bounds__(BLOCK, 2)
void nn_fused(const float2* __restrict__ pos1,
              const float2* __restrict__ pos2,
              unsigned int* __restrict__ keys,    // [N1], init 0xFF...
              unsigned int* __restrict__ ticket,  // init 0xFFFFFFFF (memset'd with keys)
              float* __restrict__ out) {
    const int ib   = blockIdx.x & (I_BLOCKS - 1);
    const int sg   = blockIdx.x / I_BLOCKS;
    const int t    = threadIdx.x;
    const int lane = t & 63;

    // prologue: p points (x,y pre-scaled by -2) and first q chunk
    const int i0 = ib * (BLOCK * PTS) + t;
    float xs[PTS], ys[PTS], m[PTS];
#pragma unroll
    for (int k = 0; k < PTS; ++k) {
        float2 p = pos1[i0 + k * BLOCK];
        xs[k] = -2.f * p.x;
        ys[k] = -2.f * p.y;
        m[k]  = 3.4e38f;
    }
    const float2* qb = pos2 + sg * QG;
    int qxc, qyc;
    {
        float2 q = qb[lane];
        qxc = __float_as_int(q.x);
        qyc = __float_as_int(q.y);
    }

    for (int c = 0; c < NCHUNK; ++c) {
        // prefetch next chunk while computing this one (latency fully hidden)
        const int cn = (c + 1 < NCHUNK) ? c + 1 : c;
        float2 qn = qb[cn * 64 + lane];
        int qxn = __float_as_int(qn.x), qyn = __float_as_int(qn.y);

#pragma unroll
        for (int j = 0; j < 64; j += 2) {
            v2f ax, ay;
            ax.x = __int_as_float(__builtin_amdgcn_readlane(qxc, j));
            ay.x = __int_as_float(__builtin_amdgcn_readlane(qyc, j));
            ax.y = __int_as_float(__builtin_amdgcn_readlane(qxc, j + 1));
            ay.y = __int_as_float(__builtin_amdgcn_readlane(qyc, j + 1));
            v2f az = __builtin_elementwise_fma(ax, ax, ay * ay);
#pragma unroll
            for (int k = 0; k < PTS; ++k) {
                v2f xk = (v2f){xs[k], xs[k]};
                v2f yk = (v2f){ys[k], ys[k]};
                v2f g = __builtin_elementwise_fma(
                            xk, ax, __builtin_elementwise_fma(yk, ay, az));
                m[k] = fminf(m[k], fminf(g.x, g.y));   // -> v_min3_f32
            }
        }
        qxc = qxn; qyc = qyn;
    }

#pragma unroll
    for (int k = 0; k < PTS; ++k) {
        atomicMin(&keys[i0 + k * BLOCK], f2key(m[k]));  // fire-and-forget
    }

    // ---- ticket: last block finalizes ----
    __shared__ int lastflag;
    __threadfence();       // release: drain this thread's atomics
    __syncthreads();       // all threads of block fenced before ticket bump
    if (t == 0) {
        unsigned int old = __hip_atomic_fetch_add(
            ticket, 1u, __ATOMIC_ACQ_REL, __HIP_MEMORY_SCOPE_AGENT);
        // ticket starts at 0xFFFFFFFF (memset 0xFF): arrival n sees n-2;
        // the GRID-th (last) arrival sees GRID-2.
        lastflag = (old == (unsigned)(GRID - 2));
    }
    __syncthreads();
    if (!lastflag) return;
    __threadfence();       // acquire

    float sum = 0.f;
#pragma unroll 4
    for (int r = 0; r < N1 / BLOCK; ++r) {
        const int i = r * BLOCK + t;
        unsigned int kk = __hip_atomic_load(&keys[i], __ATOMIC_RELAXED,
                                            __HIP_MEMORY_SCOPE_AGENT);
        float g = key2f(kk);
        float2 p = pos1[i];
        sum += sqrtf(fmaxf(fmaf(p.x, p.x, p.y * p.y) + g, 0.f));
    }
    for (int off = 32; off > 0; off >>= 1) {
        sum += __shfl_down(sum, off, 64);
    }
    __shared__ float ws4[BLOCK / 64];
    if ((t & 63) == 0) ws4[t >> 6] = sum;
    __syncthreads();
    if (t == 0) {
        float s = 0.f;
        for (int w = 0; w < BLOCK / 64; ++w) s += ws4[w];
        out[0] = s / (float)N1;
    }
}

extern "C" void kernel_launch(void* const* d_in, const int* in_sizes, int n_in,
                              void* d_out, int out_size, void* d_ws, size_t ws_size,
                              hipStream_t stream) {
    const float2* pos1 = (const float2*)d_in[0];
    const float2* pos2 = (const float2*)d_in[1];
    float* out = (float*)d_out;

    unsigned int* keys   = (unsigned int*)d_ws;   // N1 uints (64 KB)
    unsigned int* ticket = keys + N1;             // 1 uint, shares the memset

    // keys -> 0xFFFFFFFF (+inf ordering), ticket -> 0xFFFFFFFF (counts from -1)
    hipMemsetAsync(keys, 0xFF, (size_t)(N1 + 1) * sizeof(unsigned int), stream);

    nn_fused<<<GRID, BLOCK, 0, stream>>>(pos1, pos2, keys, ticket, out);
}

// Round 8
// 113.445 us; speedup vs baseline: 1.0453x; 1.0453x over previous
//
#include <hip/hip_runtime.h>
#include <math.h>

#define N1 16384
#define N2 16384
#define BLOCK 256
#define PTS 16                         // pos1 points per thread
#define HP (PTS / 2)                   // 8 packed v2f chains
#define I_BLOCKS (N1 / (BLOCK * PTS))  // 4 blocks along pos1
#define SLICES 128                     // pos2 slices
#define GRID (I_BLOCKS * SLICES)       // 512 blocks = 2 blocks/CU
#define SLICE_N (N2 / SLICES)          // 128 q points per slice

typedef float v2f __attribute__((ext_vector_type(2)));

// order-preserving float<->uint mapping (atomicMin over possibly-negative g)
static __device__ __forceinline__ unsigned int f2key(float f) {
    unsigned int b = __float_as_uint(f);
    return (b & 0x80000000u) ? ~b : (b | 0x80000000u);
}
static __device__ __forceinline__ float key2f(unsigned int k) {
    unsigned int b = (k & 0x80000000u) ? (k & 0x7FFFFFFFu) : ~k;
    return __uint_as_float(b);
}

// Phase 1: per (i-block, slice): min over 128 pos2 points of
//   g(q) = -2 p.q + |q|^2        (d^2 = |p|^2 + g; shift applied in phase 2)
// q staged in LDS PRE-TRANSFORMED to (-2qx,-2qy,|q|^2): inner loop is one
// broadcast ds_read_b128 per q + pure VGPR packed math (v_pk_fma_f32 over
// pairs of p points) -- no scalar loads (r4-r6 lgkmcnt(0) wall), no readlane
// (r7 SGPR-hazard wall), and half the r2 LDS traffic per pair (PTS=16).
// Combine: device-scope atomicMin on 64 KB keys. Phase 2: ticket, last block
// reduces keys -> mean.
__global__ __launch_bounds__(BLOCK, 2)
void nn_fused(const float2* __restrict__ pos1,
              const float2* __restrict__ pos2,
              unsigned int* __restrict__ keys,    // [N1], memset 0xFF
              unsigned int* __restrict__ ticket,  // memset 0xFF (counts from -1)
              float* __restrict__ out) {
    __shared__ float4 sp[SLICE_N];
    const int ib = blockIdx.x & (I_BLOCKS - 1);
    const int sg = blockIdx.x / I_BLOCKS;
    const int t  = threadIdx.x;

    // stage + transform this block's q slice (128 points, threads 0..127)
    if (t < SLICE_N) {
        float2 q = pos2[sg * SLICE_N + t];
        sp[t] = make_float4(-2.f * q.x, -2.f * q.y,
                            fmaf(q.x, q.x, q.y * q.y), 0.f);
    }

    // p points as packed pairs: x2[h] = (x_{2h}, x_{2h+1}) etc.
    const int i0 = ib * (BLOCK * PTS) + t;
    v2f x2[HP], y2[HP], m2[HP];
#pragma unroll
    for (int h = 0; h < HP; ++h) {
        float2 pa = pos1[i0 + (2 * h) * BLOCK];
        float2 pb = pos1[i0 + (2 * h + 1) * BLOCK];
        x2[h] = (v2f){pa.x, pb.x};
        y2[h] = (v2f){pa.y, pb.y};
        m2[h] = (v2f){3.4e38f, 3.4e38f};
    }
    __syncthreads();

#pragma unroll 4
    for (int j = 0; j < SLICE_N; ++j) {
        float4 a = sp[j];               // broadcast ds_read_b128, no conflicts
        v2f ax = (v2f){a.x, a.x};
        v2f ay = (v2f){a.y, a.y};
        v2f az = (v2f){a.z, a.z};
#pragma unroll
        for (int h = 0; h < HP; ++h) {
            v2f g = __builtin_elementwise_fma(
                        x2[h], ax, __builtin_elementwise_fma(y2[h], ay, az));
            m2[h] = __builtin_elementwise_min(m2[h], g);
        }
    }

#pragma unroll
    for (int h = 0; h < HP; ++h) {
        atomicMin(&keys[i0 + (2 * h) * BLOCK],     f2key(m2[h].x));
        atomicMin(&keys[i0 + (2 * h + 1) * BLOCK], f2key(m2[h].y));
    }

    // ---- ticket: last block finalizes ----
    __shared__ int lastflag;
    __threadfence();       // release: drain this thread's atomics
    __syncthreads();
    if (t == 0) {
        unsigned int old = __hip_atomic_fetch_add(
            ticket, 1u, __ATOMIC_ACQ_REL, __HIP_MEMORY_SCOPE_AGENT);
        // ticket starts at 0xFFFFFFFF: n-th arrival sees n-2; last sees GRID-2
        lastflag = (old == (unsigned)(GRID - 2));
    }
    __syncthreads();
    if (!lastflag) return;
    __threadfence();       // acquire

    float s0 = 0.f, s1 = 0.f;
#pragma unroll 8
    for (int r = 0; r < N1 / BLOCK; ++r) {   // independent loads -> batched
        const int i = r * BLOCK + t;
        unsigned int kk = __hip_atomic_load(&keys[i], __ATOMIC_RELAXED,
                                            __HIP_MEMORY_SCOPE_AGENT);
        float g = key2f(kk);
        float2 p = pos1[i];
        float d = sqrtf(fmaxf(fmaf(p.x, p.x, p.y * p.y) + g, 0.f));
        if (r & 1) s1 += d; else s0 += d;
    }
    float sum = s0 + s1;
    for (int off = 32; off > 0; off >>= 1) {
        sum += __shfl_down(sum, off, 64);
    }
    __shared__ float ws4[BLOCK / 64];
    if ((t & 63) == 0) ws4[t >> 6] = sum;
    __syncthreads();
    if (t == 0) {
        float s = 0.f;
        for (int w = 0; w < BLOCK / 64; ++w) s += ws4[w];
        out[0] = s / (float)N1;
    }
}

extern "C" void kernel_launch(void* const* d_in, const int* in_sizes, int n_in,
                              void* d_out, int out_size, void* d_ws, size_t ws_size,
                              hipStream_t stream) {
    const float2* pos1 = (const float2*)d_in[0];
    const float2* pos2 = (const float2*)d_in[1];
    float* out = (float*)d_out;

    unsigned int* keys   = (unsigned int*)d_ws;   // N1 uints (64 KB)
    unsigned int* ticket = keys + N1;             // shares the memset

    // keys -> 0xFFFFFFFF (+inf ordering), ticket -> 0xFFFFFFFF
    hipMemsetAsync(keys, 0xFF, (size_t)(N1 + 1) * sizeof(unsigned int), stream);

    nn_fused<<<GRID, BLOCK, 0, stream>>>(pos1, pos2, keys, ticket, out);
}

// Round 9
// 95.594 us; speedup vs baseline: 1.2404x; 1.1867x over previous
//
#include <hip/hip_runtime.h>
#include <math.h>

#define N1 16384
#define N2 16384
#define BLOCK 256
#define PTS 8                          // pos1 points per thread
#define HP (PTS / 2)                   // 4 packed v2f chains (pairs of p)
#define I_BLOCKS (N1 / (BLOCK * PTS))  // 8 blocks along pos1
#define SLICES 128                     // pos2 slices
#define GRID1 (I_BLOCKS * SLICES)      // 1024 blocks = 4 blocks/CU
#define SLICE_N (N2 / SLICES)          // 128 q per slice
#define SLICE_F4 (SLICE_N / 2)         // 64 float4 = 2 q each

typedef float v2f __attribute__((ext_vector_type(2)));

// Stage 1: per (i-block, slice): for 2048 pos1 points, min over 128 pos2
// points of g(q) = -2 p.q + |q|^2  (d^2 = |p|^2 + g, shift applied in stage 2).
// Inner loop: one broadcast ds_read_b128 = TWO raw q points; per chain of
// two p's: 4 v_pk_fma_f32 + 2 v_min3_f32 -> 1.5 instr/pair. Epilogue is
// PLAIN coalesced stores (r8's lesson: 2M memory-side atomicMin RMWs over
// 1K lines serialize ~50us; stores are ~1.3us of BW).
__global__ __launch_bounds__(BLOCK, 4)
void nn_partial(const float2* __restrict__ pos1,
                const float2* __restrict__ pos2,
                float* __restrict__ partials,
                float* __restrict__ out) {
    __shared__ float2 sq[SLICE_N];
    const int ib = blockIdx.x & (I_BLOCKS - 1);
    const int sg = blockIdx.x / I_BLOCKS;
    const int t  = threadIdx.x;

    if (blockIdx.x == 0 && t == 0) out[0] = 0.f;  // d_out is re-poisoned

    if (t < SLICE_N) sq[t] = pos2[sg * SLICE_N + t];

    const int i0 = ib * (BLOCK * PTS) + t;
    v2f x2[HP], y2[HP];
    float m[PTS];
#pragma unroll
    for (int h = 0; h < HP; ++h) {
        float2 pa = pos1[i0 + (2 * h) * BLOCK];
        float2 pb = pos1[i0 + (2 * h + 1) * BLOCK];
        x2[h] = (v2f){pa.x, pb.x};
        y2[h] = (v2f){pa.y, pb.y};
        m[2 * h] = 3.4e38f;
        m[2 * h + 1] = 3.4e38f;
    }
    __syncthreads();

    const float4* sp4 = (const float4*)sq;   // 2 q per read
#pragma unroll 4
    for (int jj = 0; jj < SLICE_F4; ++jj) {
        float4 qq = sp4[jj];                 // broadcast ds_read_b128
        float az0 = fmaf(qq.x, qq.x, qq.y * qq.y);
        float az1 = fmaf(qq.z, qq.z, qq.w * qq.w);
        v2f ax0 = (v2f){-2.f * qq.x, -2.f * qq.x};
        v2f ay0 = (v2f){-2.f * qq.y, -2.f * qq.y};
        v2f az0v = (v2f){az0, az0};
        v2f ax1 = (v2f){-2.f * qq.z, -2.f * qq.z};
        v2f ay1 = (v2f){-2.f * qq.w, -2.f * qq.w};
        v2f az1v = (v2f){az1, az1};
#pragma unroll
        for (int h = 0; h < HP; ++h) {
            v2f g0 = __builtin_elementwise_fma(
                         x2[h], ax0, __builtin_elementwise_fma(y2[h], ay0, az0v));
            v2f g1 = __builtin_elementwise_fma(
                         x2[h], ax1, __builtin_elementwise_fma(y2[h], ay1, az1v));
            m[2 * h]     = fminf(m[2 * h],     fminf(g0.x, g1.x));  // v_min3
            m[2 * h + 1] = fminf(m[2 * h + 1], fminf(g0.y, g1.y));  // v_min3
        }
    }

#pragma unroll
    for (int k = 0; k < PTS; ++k) {
        partials[(size_t)sg * N1 + i0 + k * BLOCK] = m[k];  // coalesced store
    }
}

// Stage 2: 64 blocks; thread owns one pos1 point. Coalesced, 8-deep-batched
// min over 128 slice partials (r4's serial-chain mistake fixed), + |p|^2,
// sqrt, block reduce, one fp32 atomicAdd per block into out (zeroed by
// stage 1; kernel boundary orders it).
__global__ __launch_bounds__(BLOCK)
void nn_reduce(const float* __restrict__ partials,
               const float2* __restrict__ pos1,
               float* __restrict__ out) {
    const int t = threadIdx.x;
    const int i = blockIdx.x * BLOCK + t;

    float m = 3.4e38f;
#pragma unroll 8
    for (int s = 0; s < SLICES; ++s) {       // independent -> batched loads
        m = fminf(m, partials[(size_t)s * N1 + i]);
    }
    float2 p = pos1[i];
    float sum = sqrtf(fmaxf(fmaf(p.x, p.x, p.y * p.y) + m, 0.f));

    for (int off = 32; off > 0; off >>= 1) {
        sum += __shfl_down(sum, off, 64);
    }
    __shared__ float ws4[BLOCK / 64];
    if ((t & 63) == 0) ws4[t >> 6] = sum;
    __syncthreads();
    if (t == 0) {
        float s = 0.f;
        for (int w = 0; w < BLOCK / 64; ++w) s += ws4[w];
        atomicAdd(out, s * (1.f / (float)N1));   // 64 atomics total
    }
}

extern "C" void kernel_launch(void* const* d_in, const int* in_sizes, int n_in,
                              void* d_out, int out_size, void* d_ws, size_t ws_size,
                              hipStream_t stream) {
    const float2* pos1 = (const float2*)d_in[0];
    const float2* pos2 = (const float2*)d_in[1];
    float* out = (float*)d_out;
    float* partials = (float*)d_ws;   // SLICES * N1 floats = 8 MB, no init needed

    nn_partial<<<GRID1, BLOCK, 0, stream>>>(pos1, pos2, partials, out);
    nn_reduce<<<N1 / BLOCK, BLOCK, 0, stream>>>(partials, pos1, out);
}

// Round 10
// 78.542 us; speedup vs baseline: 1.5098x; 1.2171x over previous
//
#include <hip/hip_runtime.h>
#include <math.h>

#define N1 16384
#define N2 16384
#define BLOCK 256
#define PTS 8                          // pos1 points per thread
#define I_BLOCKS (N1 / (BLOCK * PTS))  // 8 blocks along pos1
#define SLICES 128                     // pos2 slices -> 1024 blocks, 4 waves/SIMD
#define SLICE_N (N2 / SLICES)          // 128 q per slice
#define SLICE_F4 (SLICE_N / 2)         // 64 ds_read_b128, 2 q each

// order-preserving float<->uint mapping (atomicMin over possibly-negative g)
static __device__ __forceinline__ unsigned int f2key(float f) {
    unsigned int b = __float_as_uint(f);
    return (b & 0x80000000u) ? ~b : (b | 0x80000000u);
}
static __device__ __forceinline__ float key2f(unsigned int k) {
    unsigned int b = (k & 0x80000000u) ? (k & 0x7FFFFFFFu) : ~k;
    return __uint_as_float(b);
}

// Stage 1: per (i-block, slice): min over 128 pos2 points of
//   g(q) = -2 p.q + |q|^2     (d^2 = |p|^2 + g; shift applied in stage 2).
// q staged RAW in LDS (1 KB), read as broadcast ds_read_b128 = 2 q's/read
// (no scalar-load lgkmcnt(0) drains, no readlane SGPR hazards). Math is all
// SCALAR full-rate fp32 (pk fp32 is 2 issue slots on CDNA4 -> no cycle win):
// per 2 q's: 6 prep + 8 x (4 fma + 1 v_min3) = 2.875 instr/pair.
// Combine: fire-and-forget device-scope atomicMin on 64 KB keys (r5 path,
// measured-best; 2M atomics fit the budget).
__global__ __launch_bounds__(BLOCK, 4)
void nn_partial(const float2* __restrict__ pos1,
                const float2* __restrict__ pos2,
                unsigned int* __restrict__ keys,
                unsigned int* __restrict__ ticket,
                float* __restrict__ out) {
    __shared__ float2 sq[SLICE_N];
    const int ib = blockIdx.x & (I_BLOCKS - 1);
    const int sg = blockIdx.x / I_BLOCKS;
    const int t  = threadIdx.x;

    if (ib == 0 && sg == 0 && t == 0) *ticket = 0;  // init for stage 2

    if (t < SLICE_N) sq[t] = pos2[sg * SLICE_N + t];

    const int i0 = ib * (BLOCK * PTS) + t;
    float x[PTS], y[PTS], m[PTS];
#pragma unroll
    for (int k = 0; k < PTS; ++k) {
        float2 p = pos1[i0 + k * BLOCK];
        x[k] = p.x; y[k] = p.y; m[k] = 3.4e38f;
    }
    __syncthreads();

    const float4* sp4 = (const float4*)sq;   // 2 raw q per 16B read
#pragma unroll 4
    for (int jj = 0; jj < SLICE_F4; ++jj) {
        float4 qq = sp4[jj];                 // broadcast ds_read_b128
        float ax0 = -2.f * qq.x, ay0 = -2.f * qq.y;
        float az0 = fmaf(qq.x, qq.x, qq.y * qq.y);
        float ax1 = -2.f * qq.z, ay1 = -2.f * qq.w;
        float az1 = fmaf(qq.z, qq.z, qq.w * qq.w);
#pragma unroll
        for (int k = 0; k < PTS; ++k) {
            float g0 = fmaf(x[k], ax0, fmaf(y[k], ay0, az0));
            float g1 = fmaf(x[k], ax1, fmaf(y[k], ay1, az1));
            m[k] = fminf(m[k], fminf(g0, g1));   // -> v_min3_f32
        }
    }

#pragma unroll
    for (int k = 0; k < PTS; ++k) {
        atomicMin(&keys[i0 + k * BLOCK], f2key(m[k]));  // fire-and-forget
    }
}

// Stage 2 (fused final): 64 blocks; decode key, + |p|^2, sqrt, block-sum;
// last block (ticket) reduces the 64 block sums and writes the mean.
__global__ __launch_bounds__(BLOCK)
void nn_finish(const unsigned int* __restrict__ keys,
               const float2* __restrict__ pos1,
               float* __restrict__ blocksums,
               unsigned int* __restrict__ ticket,
               float* __restrict__ out) {
    const int t = threadIdx.x;
    const int i = blockIdx.x * BLOCK + t;

    float g = key2f(keys[i]);
    float2 p = pos1[i];
    float d2 = fmaxf(fmaf(p.x, p.x, p.y * p.y) + g, 0.f);
    float sum = sqrtf(d2);

    for (int off = 32; off > 0; off >>= 1) {
        sum += __shfl_down(sum, off, 64);
    }
    __shared__ float wsum[BLOCK / 64];
    __shared__ int lastflag;
    if ((t & 63) == 0) wsum[t >> 6] = sum;
    __syncthreads();
    if (t == 0) {
        float s = 0.f;
        for (int w = 0; w < BLOCK / 64; ++w) s += wsum[w];
        blocksums[blockIdx.x] = s;
        __threadfence();
        unsigned int old = atomicAdd(ticket, 1u);
        lastflag = (old == gridDim.x - 1) ? 1 : 0;
    }
    __syncthreads();
    if (lastflag && t < 64) {
        volatile float* vb = (volatile float*)blocksums;
        float v = vb[t];
        for (int off = 32; off > 0; off >>= 1) {
            v += __shfl_down(v, off, 64);
        }
        if (t == 0) out[0] = v / (float)N1;
    }
}

extern "C" void kernel_launch(void* const* d_in, const int* in_sizes, int n_in,
                              void* d_out, int out_size, void* d_ws, size_t ws_size,
                              hipStream_t stream) {
    const float2* pos1 = (const float2*)d_in[0];
    const float2* pos2 = (const float2*)d_in[1];
    float* out = (float*)d_out;

    unsigned int* keys   = (unsigned int*)d_ws;   // N1 uints (64 KB)
    float* blocksums     = (float*)(keys + N1);   // 64 floats
    unsigned int* ticket = (unsigned int*)(blocksums + 64);

    // keys -> 0xFFFFFFFF (+inf ordering); ticket re-zeroed by stage 1
    hipMemsetAsync(keys, 0xFF, (size_t)N1 * sizeof(unsigned int), stream);

    nn_partial<<<dim3(I_BLOCKS * SLICES), BLOCK, 0, stream>>>(
        pos1, pos2, keys, ticket, out);
    nn_finish<<<N1 / BLOCK, BLOCK, 0, stream>>>(keys, pos1, blocksums, ticket, out);
}